// Round 1
// baseline (1419.304 us; speedup 1.0000x reference)
//
#include <hip/hip_runtime.h>
#include <math.h>

#define LSEQ 1280
#define L0SEQ 1250
#define DM 64
#define NHEADS 4
#define DHD 16
#define NHASH 4
#define NBUK 20
#define NCHUNK 80
#define FFD 256
#define NBATCH 16
#define NBH 64

#define XSZ (NBATCH*LSEQ*DM)        // 1310720
#define QKSZ (NBH*LSEQ*DHD)         // 1310720
#define OHSZ (NBH*NHASH*LSEQ*DHD)   // 5242880
#define SLSZ (NBH*NHASH*LSEQ)       // 327680

// ---------------- embed: x = pad(wave^T) @ in_w + in_b ----------------
__global__ __launch_bounds__(256) void k_embed(
    const float* __restrict__ wave, const float* __restrict__ in_w,
    const float* __restrict__ in_b, float* __restrict__ x1, float* __restrict__ x2)
{
    int idx = blockIdx.x * 256 + threadIdx.x;   // over B*L*D
    int d = idx & 63;
    int t = idx >> 6;
    int b = t / LSEQ;
    int tt = t % LSEQ;
    float v0 = 0.f, v1 = 0.f;
    if (tt < L0SEQ) {
        v0 = wave[(size_t)(b*2+0)*L0SEQ + tt];
        v1 = wave[(size_t)(b*2+1)*L0SEQ + tt];
    }
    float x = v0 * in_w[d] + v1 * in_w[64 + d] + in_b[d];
    x1[idx] = x;
    x2[idx] = x;
}

// ---------------- LN + QK/V projection + LSH bucketing ----------------
// block = 64 tokens of one batch; grid 320
__global__ __launch_bounds__(256) void k_qkv(
    const float* __restrict__ x2, const float* __restrict__ g, const float* __restrict__ bta,
    const float* __restrict__ wqk, const float* __restrict__ wv, const float* __restrict__ rot,
    float* __restrict__ qk, float* __restrict__ v, int* __restrict__ buckets)
{
    __shared__ float xln[64][65];
    __shared__ float qkt[64][65];
    __shared__ float rots[640];
    __shared__ float psum[64][4];
    __shared__ float psq[64][4];
    int tid = threadIdx.x;
    int b  = blockIdx.x / 20;
    int t0 = (blockIdx.x % 20) * 64;
    const float* xbase = x2 + (size_t)(b*LSEQ + t0)*DM;
    int r = tid >> 2, qq = tid & 3;
    float vals[16];
    float s = 0.f, ss = 0.f;
    for (int i = 0; i < 16; i++) {
        float vv = xbase[r*DM + qq*16 + i];
        vals[i] = vv; s += vv; ss += vv*vv;
    }
    psum[r][qq] = s; psq[r][qq] = ss;
    for (int i = tid; i < 640; i += 256) rots[i] = rot[i];
    __syncthreads();
    float m  = (psum[r][0]+psum[r][1]+psum[r][2]+psum[r][3]) * (1.f/64.f);
    float vr = (psq[r][0]+psq[r][1]+psq[r][2]+psq[r][3]) * (1.f/64.f) - m*m;
    float rstd = 1.f / sqrtf(vr + 1e-5f);
    for (int i = 0; i < 16; i++) {
        int c = qq*16 + i;
        xln[r][c] = (vals[i]-m)*rstd*g[c] + bta[c];
    }
    __syncthreads();
    // matmuls: thread tile = 4 tokens x 4 cols
    int cg = tid & 15, tg = tid >> 4;
    int c0 = cg*4, tl0 = tg*4;
    float aq[4][4], av[4][4];
    for (int i=0;i<4;i++) for (int j=0;j<4;j++){ aq[i][j]=0.f; av[i][j]=0.f; }
    for (int f = 0; f < 64; f++) {
        float4 wq4 = *(const float4*)&wqk[f*64 + c0];
        float4 wv4 = *(const float4*)&wv [f*64 + c0];
        float xv[4];
        for (int i=0;i<4;i++) xv[i] = xln[tl0+i][f];
        for (int i=0;i<4;i++) {
            aq[i][0] += xv[i]*wq4.x; aq[i][1] += xv[i]*wq4.y;
            aq[i][2] += xv[i]*wq4.z; aq[i][3] += xv[i]*wq4.w;
            av[i][0] += xv[i]*wv4.x; av[i][1] += xv[i]*wv4.y;
            av[i][2] += xv[i]*wv4.z; av[i][3] += xv[i]*wv4.w;
        }
    }
    int head = c0 >> 4;
    int dh0  = c0 & 15;
    for (int i=0;i<4;i++) {
        int t = t0 + tl0 + i;
        float4 q4; q4.x=aq[i][0]; q4.y=aq[i][1]; q4.z=aq[i][2]; q4.w=aq[i][3];
        float4 v4; v4.x=av[i][0]; v4.y=av[i][1]; v4.z=av[i][2]; v4.w=av[i][3];
        *(float4*)&qk[((size_t)(b*NHEADS+head)*LSEQ + t)*DHD + dh0] = q4;
        *(float4*)&v [((size_t)(b*NHEADS+head)*LSEQ + t)*DHD + dh0] = v4;
        qkt[tl0+i][c0+0] = aq[i][0]; qkt[tl0+i][c0+1] = aq[i][1];
        qkt[tl0+i][c0+2] = aq[i][2]; qkt[tl0+i][c0+3] = aq[i][3];
    }
    __syncthreads();
    // buckets: thread = (token, head)
    int ttk = tid >> 2, hh = tid & 3;
    float qf[16];
    for (int f=0; f<16; f++) qf[f] = qkt[ttk][hh*16+f];
    int tglob = t0 + ttk;
    for (int nh = 0; nh < NHASH; nh++) {
        float rv[10];
        for (int i=0;i<10;i++) {
            float acc = 0.f;
            for (int f=0; f<16; f++) acc += qf[f]*rots[(f*NHASH+nh)*10 + i];
            rv[i] = acc;
        }
        float best = rv[0]; int bi = 0;
        for (int i=1;i<10;i++) if (rv[i] > best) { best = rv[i]; bi = i; }
        for (int i=0;i<10;i++) if (-rv[i] > best) { best = -rv[i]; bi = 10+i; }
        buckets[((size_t)(b*NHEADS+hh)*NHASH + nh)*LSEQ + tglob] = bi;
    }
}

// ---------------- counting sort per (bh, hash): stable by position ----------------
// 4 waves per block, one (bh,hash) group per wave; grid 64
__global__ __launch_bounds__(256) void k_sort(
    const int* __restrict__ buckets, int* __restrict__ sorted)
{
    __shared__ int bks[4][LSEQ];
    __shared__ int hist[4][20];
    __shared__ int start[4][20];
    int wave = threadIdx.x >> 6;
    int lane = threadIdx.x & 63;
    int gidx = blockIdx.x * 4 + wave;
    const int* bk = buckets + (size_t)gidx * LSEQ;
    if (lane < 20) hist[wave][lane] = 0;
    __syncthreads();
    for (int i = lane; i < LSEQ; i += 64) {
        int bv = bk[i];
        bks[wave][i] = bv;
        atomicAdd(&hist[wave][bv], 1);
    }
    __syncthreads();
    if (lane == 0) {
        int acc = 0;
        for (int k2 = 0; k2 < 20; k2++) { start[wave][k2] = acc; acc += hist[wave][k2]; }
    }
    __syncthreads();
    if (lane < 20) {
        int outp = start[wave][lane];
        int* dst = sorted + (size_t)gidx * LSEQ;
        for (int pos = 0; pos < LSEQ; pos++) {
            if (bks[wave][pos] == lane) dst[outp++] = pos;
        }
    }
}

// ---------------- chunked attention: one (bh, chunk) per block; grid 5120 ----------------
__global__ __launch_bounds__(256) void k_attn(
    const float* __restrict__ qk, const float* __restrict__ v,
    const int* __restrict__ sorted, float* __restrict__ o_hash, float* __restrict__ slog)
{
    __shared__ float bqT[16][64];     // [f][qi], unnormalized
    __shared__ float bkT[16][128];    // [f][kj], normalized
    __shared__ float bvs[128][17];
    __shared__ float sdots[64][129];
    __shared__ int   qpos[64];
    __shared__ int   kpos[128];
    __shared__ float sinv[64];
    int tid = threadIdx.x;
    int bh = blockIdx.x / NCHUNK;
    int c  = blockIdx.x % NCHUNK;
    int h  = c / NBUK, cc = c % NBUK;
    int cp = (c + NCHUNK - 1) % NCHUNK;
    int hp = cp / NBUK, ccp = cp % NBUK;
    if (tid < 64) {
        int p = sorted[((size_t)bh*NHASH + h)*LSEQ + cc*64 + tid];
        qpos[tid] = p; kpos[tid] = p;
    } else if (tid < 128) {
        int j = tid - 64;
        kpos[64+j] = sorted[((size_t)bh*NHASH + hp)*LSEQ + ccp*64 + j];
    }
    __syncthreads();
    if (tid < 128) {
        int pos = kpos[tid];
        const float* qrow = qk + ((size_t)bh*LSEQ + pos)*DHD;
        float rr[16]; float nsq = 0.f;
        for (int f=0; f<16; f++){ rr[f] = qrow[f]; nsq += rr[f]*rr[f]; }
        if (tid < 64) for (int f=0; f<16; f++) bqT[f][tid] = rr[f];
        float inv = 1.f / fmaxf(sqrtf(nsq), 1e-12f);
        for (int f=0; f<16; f++) bkT[f][tid] = rr[f]*inv;
        const float* vrow = v + ((size_t)bh*LSEQ + pos)*DHD;
        for (int f=0; f<16; f++) bvs[tid][f] = vrow[f];
    }
    __syncthreads();
    // dots 64x128: thread tile 4q x 8k
    {
        int qt = tid >> 4, kt = tid & 15;
        int qi0 = qt*4, kj0 = kt*8;
        float acc[4][8];
        for (int i=0;i<4;i++) for (int j=0;j<8;j++) acc[i][j]=0.f;
        for (int f=0; f<16; f++) {
            float4 q4  = *(const float4*)&bqT[f][qi0];
            float4 k4a = *(const float4*)&bkT[f][kj0];
            float4 k4b = *(const float4*)&bkT[f][kj0+4];
            float qv[4] = {q4.x, q4.y, q4.z, q4.w};
            float kv[8] = {k4a.x, k4a.y, k4a.z, k4a.w, k4b.x, k4b.y, k4b.z, k4b.w};
            for (int i=0;i<4;i++)
                for (int j=0;j<8;j++)
                    acc[i][j] += qv[i]*kv[j];
        }
        for (int i=0;i<4;i++) for (int j=0;j<8;j++) {
            float dd = acc[i][j]*0.25f;
            if (qpos[qi0+i] == kpos[kj0+j]) dd = -5e4f;
            sdots[qi0+i][kj0+j] = dd;
        }
    }
    __syncthreads();
    // per-row logsumexp + convert row to exp(d - max)
    if (tid < 64) {
        float mx = -3.4e38f;
        for (int j=0;j<128;j++) mx = fmaxf(mx, sdots[tid][j]);
        float s = 0.f;
        for (int j=0;j<128;j++){ float p = expf(sdots[tid][j]-mx); sdots[tid][j]=p; s+=p; }
        float lse = mx + logf(s);
        slog[((size_t)bh*NHASH + h)*LSEQ + qpos[tid]] = lse;
        sinv[tid] = 1.f/s;
    }
    __syncthreads();
    // bo = probs @ bv, scatter by original position
    {
        int qi = tid >> 2, d0 = (tid & 3)*4;
        float o0=0.f, o1=0.f, o2=0.f, o3=0.f;
        for (int j=0;j<128;j++){
            float p = sdots[qi][j];
            o0 += p*bvs[j][d0+0];
            o1 += p*bvs[j][d0+1];
            o2 += p*bvs[j][d0+2];
            o3 += p*bvs[j][d0+3];
        }
        float iv = sinv[qi];
        float4 o4; o4.x=o0*iv; o4.y=o1*iv; o4.z=o2*iv; o4.w=o3*iv;
        *(float4*)&o_hash[(((size_t)bh*NHASH + h)*LSEQ + qpos[qi])*DHD + d0] = o4;
    }
}

// ---------------- hash-round combine + output proj + residual into x1 ----------------
// block = 64 tokens of one batch; grid 320
__global__ __launch_bounds__(256) void k_combine(
    const float* __restrict__ o_hash, const float* __restrict__ slog,
    const float* __restrict__ wo_w, const float* __restrict__ wo_b, float* __restrict__ x1)
{
    __shared__ float att[64][65];
    int tid = threadIdx.x;
    int b  = blockIdx.x / 20;
    int t0 = (blockIdx.x % 20) * 64;
    int ttk = tid >> 2, head = tid & 3;
    int t = t0 + ttk;
    int bh = b*NHEADS + head;
    float sl[4];
    for (int nh=0;nh<4;nh++) sl[nh] = slog[((size_t)bh*NHASH + nh)*LSEQ + t];
    float mx = fmaxf(fmaxf(sl[0],sl[1]), fmaxf(sl[2],sl[3]));
    float wsum = 0.f; float wv[4];
    for (int nh=0;nh<4;nh++){ wv[nh] = expf(sl[nh]-mx); wsum += wv[nh]; }
    float invs = 1.f/wsum;
    float a[16];
    for (int d=0;d<16;d++) a[d]=0.f;
    for (int nh=0;nh<4;nh++){
        const float4* orow = (const float4*)(o_hash + (((size_t)bh*NHASH + nh)*LSEQ + t)*DHD);
        float wn = wv[nh]*invs;
        float4 A=orow[0], B=orow[1], C=orow[2], Dq=orow[3];
        a[0]+=wn*A.x;  a[1]+=wn*A.y;  a[2]+=wn*A.z;  a[3]+=wn*A.w;
        a[4]+=wn*B.x;  a[5]+=wn*B.y;  a[6]+=wn*B.z;  a[7]+=wn*B.w;
        a[8]+=wn*C.x;  a[9]+=wn*C.y;  a[10]+=wn*C.z; a[11]+=wn*C.w;
        a[12]+=wn*Dq.x;a[13]+=wn*Dq.y;a[14]+=wn*Dq.z;a[15]+=wn*Dq.w;
    }
    for (int d=0;d<16;d++) att[ttk][head*16+d] = a[d];
    __syncthreads();
    int cg = tid & 15, tg = tid >> 4;
    int c0 = cg*4, tl0 = tg*4;
    float acc[4][4];
    for (int i=0;i<4;i++) for (int j=0;j<4;j++) acc[i][j]=0.f;
    for (int f=0; f<64; f++){
        float4 w4 = *(const float4*)&wo_w[f*64 + c0];
        float xv[4];
        for (int i=0;i<4;i++) xv[i] = att[tl0+i][f];
        for (int i=0;i<4;i++){
            acc[i][0]+=xv[i]*w4.x; acc[i][1]+=xv[i]*w4.y;
            acc[i][2]+=xv[i]*w4.z; acc[i][3]+=xv[i]*w4.w;
        }
    }
    float4 bb = *(const float4*)&wo_b[c0];
    for (int i=0;i<4;i++){
        size_t idx = ((size_t)b*LSEQ + (t0 + tl0 + i))*DM + c0;
        float4 cur = *(float4*)&x1[idx];
        cur.x += acc[i][0]+bb.x; cur.y += acc[i][1]+bb.y;
        cur.z += acc[i][2]+bb.z; cur.w += acc[i][3]+bb.w;
        *(float4*)&x1[idx] = cur;
    }
}

// ---------------- LN2 + W1 + gelu -> mid ----------------
// block = 32 tokens; grid 640
__global__ __launch_bounds__(256) void k_ff1(
    const float* __restrict__ x1, const float* __restrict__ g, const float* __restrict__ bta,
    const float* __restrict__ w1, const float* __restrict__ b1, float* __restrict__ mid)
{
    __shared__ float w1s[16*256];
    __shared__ float xln[32][65];
    __shared__ float ps[32][8], pq[32][8];
    int tid = threadIdx.x;
    int tbase = blockIdx.x * 32;
    int r = tid >> 3, qq = tid & 7;
    const float* xr = x1 + (size_t)(tbase + r)*DM;
    float vals[8]; float s = 0.f, ss = 0.f;
    for (int i=0;i<8;i++){ float vv = xr[qq*8+i]; vals[i]=vv; s+=vv; ss+=vv*vv; }
    ps[r][qq]=s; pq[r][qq]=ss;
    __syncthreads();
    float m=0.f, vr=0.f;
    for (int k2=0;k2<8;k2++){ m+=ps[r][k2]; vr+=pq[r][k2]; }
    m *= (1.f/64.f); vr = vr*(1.f/64.f) - m*m;
    float rstd = 1.f/sqrtf(vr+1e-5f);
    for (int i=0;i<8;i++){ int cidx=qq*8+i; xln[r][cidx] = (vals[i]-m)*rstd*g[cidx]+bta[cidx]; }
    float acc[4][8];
    for (int i=0;i<4;i++) for (int k2=0;k2<8;k2++) acc[i][k2]=0.f;
    int tg = tid >> 5;      // 8 groups of 4 tokens
    int cg = tid & 31;      // out col = cg + 32*k2
    int tl0 = tg*4;
    for (int fc = 0; fc < 4; fc++) {
        __syncthreads();
        for (int j = tid; j < 1024; j += 256)
            *(float4*)&w1s[j*4] = *(const float4*)&w1[fc*4096 + j*4];
        __syncthreads();
        for (int fl = 0; fl < 16; fl++) {
            int f = fc*16 + fl;
            float xv[4];
            for (int i=0;i<4;i++) xv[i] = xln[tl0+i][f];
            for (int k2=0;k2<8;k2++) {
                float wvv = w1s[fl*256 + cg + 32*k2];
                for (int i=0;i<4;i++) acc[i][k2] += xv[i]*wvv;
            }
        }
    }
    for (int k2=0;k2<8;k2++){
        int cidx = cg + 32*k2;
        float bb = b1[cidx];
        for (int i=0;i<4;i++){
            float xx = acc[i][k2] + bb;
            float ge = 0.5f*xx*(1.f + erff(xx*0.70710678118654752f));
            mid[(size_t)(tbase + tl0 + i)*FFD + cidx] = ge;
        }
    }
}

// ---------------- mid @ W2 + b2 -> residual into x2 ----------------
// block = 64 tokens; grid 320
__global__ __launch_bounds__(256) void k_ff2(
    const float* __restrict__ mid, const float* __restrict__ w2, const float* __restrict__ b2,
    float* __restrict__ x2)
{
    __shared__ float mids[64][65];
    int tid = threadIdx.x;
    int tbase = blockIdx.x * 64;
    int tg = tid >> 4, cg = tid & 15;
    int tl0 = tg*4, c0 = cg*4;
    float acc[4][4];
    for (int i=0;i<4;i++) for (int j=0;j<4;j++) acc[i][j]=0.f;
    for (int fc = 0; fc < 4; fc++) {
        __syncthreads();
        for (int j = tid; j < 1024; j += 256) {
            int row = j >> 4; int col4 = (j & 15) * 4;
            float4 vv = *(const float4*)&mid[(size_t)(tbase+row)*FFD + fc*64 + col4];
            mids[row][col4+0]=vv.x; mids[row][col4+1]=vv.y;
            mids[row][col4+2]=vv.z; mids[row][col4+3]=vv.w;
        }
        __syncthreads();
        for (int fl = 0; fl < 64; fl++) {
            float4 wv4 = *(const float4*)&w2[(fc*64+fl)*64 + c0];
            float mv[4];
            for (int i=0;i<4;i++) mv[i] = mids[tl0+i][fl];
            for (int i=0;i<4;i++){
                acc[i][0]+=mv[i]*wv4.x; acc[i][1]+=mv[i]*wv4.y;
                acc[i][2]+=mv[i]*wv4.z; acc[i][3]+=mv[i]*wv4.w;
            }
        }
    }
    float4 bb = *(const float4*)&b2[c0];
    for (int i=0;i<4;i++){
        size_t idx = ((size_t)(tbase + tl0 + i))*DM + c0;
        float4 cur = *(float4*)&x2[idx];
        cur.x += acc[i][0]+bb.x; cur.y += acc[i][1]+bb.y;
        cur.z += acc[i][2]+bb.z; cur.w += acc[i][3]+bb.w;
        *(float4*)&x2[idx] = cur;
    }
}

// ---------------- output proj: y = 0.5*(x1+x2) @ out_w + out_b, crop to 1250 ----------------
__global__ __launch_bounds__(256) void k_out(
    const float* __restrict__ x1, const float* __restrict__ x2,
    const float* __restrict__ out_w, const float* __restrict__ out_b, float* __restrict__ y)
{
    int idx = blockIdx.x * 256 + threadIdx.x;
    if (idx >= NBATCH * L0SEQ) return;
    int b = idx / L0SEQ, t = idx % L0SEQ;
    const float* r1 = x1 + ((size_t)b*LSEQ + t)*DM;
    const float* r2 = x2 + ((size_t)b*LSEQ + t)*DM;
    float s = 0.f;
    for (int d = 0; d < DM; d++) s += (r1[d]+r2[d])*0.5f*out_w[d];
    y[idx] = s + out_b[0];
}

extern "C" void kernel_launch(void* const* d_in, const int* in_sizes, int n_in,
                              void* d_out, int out_size, void* d_ws, size_t ws_size,
                              hipStream_t stream)
{
    const float* wave  = (const float*)d_in[0];
    const float* in_w  = (const float*)d_in[1];
    const float* in_b  = (const float*)d_in[2];
    const float* ln1_g = (const float*)d_in[3];
    const float* ln1_b = (const float*)d_in[4];
    const float* wqk   = (const float*)d_in[5];
    const float* wv    = (const float*)d_in[6];
    const float* wo_w  = (const float*)d_in[7];
    const float* wo_b  = (const float*)d_in[8];
    const float* rot   = (const float*)d_in[9];
    const float* ln2_g = (const float*)d_in[10];
    const float* ln2_b = (const float*)d_in[11];
    const float* w1    = (const float*)d_in[12];
    const float* b1    = (const float*)d_in[13];
    const float* w2    = (const float*)d_in[14];
    const float* b2    = (const float*)d_in[15];
    const float* out_w = (const float*)d_in[16];
    const float* out_b = (const float*)d_in[17];
    float* y = (float*)d_out;

    float* ws = (float*)d_ws;
    float* x1     = ws;                  // XSZ
    float* x2     = x1 + XSZ;            // XSZ
    float* qkb    = x2 + XSZ;            // QKSZ
    float* vb     = qkb + QKSZ;          // QKSZ
    float* o_hash = vb + QKSZ;           // OHSZ
    float* slogb  = o_hash + OHSZ;       // SLSZ
    int* buckets  = (int*)(slogb + SLSZ); // SLSZ ints
    int* sorted   = buckets + SLSZ;      // SLSZ ints
    float* mid    = o_hash;              // reuse (disjoint lifetime within a layer)

    k_embed<<<XSZ/256, 256, 0, stream>>>(wave, in_w, in_b, x1, x2);
    for (int layer = 0; layer < 4; layer++) {
        k_qkv<<<320, 256, 0, stream>>>(x2, ln1_g + layer*64, ln1_b + layer*64,
                                       wqk + layer*4096, wv + layer*4096, rot + layer*640,
                                       qkb, vb, buckets);
        k_sort<<<64, 256, 0, stream>>>(buckets, sorted);
        k_attn<<<NBH*NCHUNK, 256, 0, stream>>>(qkb, vb, sorted, o_hash, slogb);
        k_combine<<<320, 256, 0, stream>>>(o_hash, slogb, wo_w + layer*4096, wo_b + layer*64, x1);
        k_ff1<<<640, 256, 0, stream>>>(x1, ln2_g + layer*64, ln2_b + layer*64,
                                       w1 + layer*16384, b1 + layer*256, mid);
        k_ff2<<<320, 256, 0, stream>>>(mid, w2 + layer*16384, b2 + layer*64, x2);
    }
    k_out<<<(NBATCH*L0SEQ + 255)/256, 256, 0, stream>>>(x1, x2, out_w, out_b, y);
}

// Round 2
// 800.688 us; speedup vs baseline: 1.7726x; 1.7726x over previous
//
#include <hip/hip_runtime.h>
#include <math.h>

#define LSEQ 1280
#define L0SEQ 1250
#define DM 64
#define NHEADS 4
#define DHD 16
#define NHASH 4
#define NBUK 20
#define NCHUNK 80
#define FFD 256
#define NBATCH 16
#define NBH 64

#define XSZ (NBATCH*LSEQ*DM)        // 1310720
#define QKSZ (NBH*LSEQ*DHD)         // 1310720
#define OHSZ (NBH*NHASH*LSEQ*DHD)   // 5242880
#define SLSZ (NBH*NHASH*LSEQ)       // 327680

// ---------------- embed: x = pad(wave^T) @ in_w + in_b ----------------
__global__ __launch_bounds__(256) void k_embed(
    const float* __restrict__ wave, const float* __restrict__ in_w,
    const float* __restrict__ in_b, float* __restrict__ x1, float* __restrict__ x2)
{
    int idx = blockIdx.x * 256 + threadIdx.x;   // over B*L*D
    int d = idx & 63;
    int t = idx >> 6;
    int b = t / LSEQ;
    int tt = t % LSEQ;
    float v0 = 0.f, v1 = 0.f;
    if (tt < L0SEQ) {
        v0 = wave[(size_t)(b*2+0)*L0SEQ + tt];
        v1 = wave[(size_t)(b*2+1)*L0SEQ + tt];
    }
    float x = v0 * in_w[d] + v1 * in_w[64 + d] + in_b[d];
    x1[idx] = x;
    x2[idx] = x;
}

// ---------------- LN + QK/V projection + LSH bucketing ----------------
// block = 64 tokens of one batch; grid 320
__global__ __launch_bounds__(256) void k_qkv(
    const float* __restrict__ x2, const float* __restrict__ g, const float* __restrict__ bta,
    const float* __restrict__ wqk, const float* __restrict__ wv, const float* __restrict__ rot,
    float* __restrict__ qk, float* __restrict__ v, int* __restrict__ buckets)
{
    __shared__ float xln[64][65];
    __shared__ float qkt[64][65];
    __shared__ float rots[640];
    __shared__ float psum[64][4];
    __shared__ float psq[64][4];
    int tid = threadIdx.x;
    int b  = blockIdx.x / 20;
    int t0 = (blockIdx.x % 20) * 64;
    const float* xbase = x2 + (size_t)(b*LSEQ + t0)*DM;
    int r = tid >> 2, qq = tid & 3;
    float vals[16];
    float s = 0.f, ss = 0.f;
    for (int i = 0; i < 16; i++) {
        float vv = xbase[r*DM + qq*16 + i];
        vals[i] = vv; s += vv; ss += vv*vv;
    }
    psum[r][qq] = s; psq[r][qq] = ss;
    for (int i = tid; i < 640; i += 256) rots[i] = rot[i];
    __syncthreads();
    float m  = (psum[r][0]+psum[r][1]+psum[r][2]+psum[r][3]) * (1.f/64.f);
    float vr = (psq[r][0]+psq[r][1]+psq[r][2]+psq[r][3]) * (1.f/64.f) - m*m;
    float rstd = 1.f / sqrtf(vr + 1e-5f);
    for (int i = 0; i < 16; i++) {
        int c = qq*16 + i;
        xln[r][c] = (vals[i]-m)*rstd*g[c] + bta[c];
    }
    __syncthreads();
    // matmuls: thread tile = 4 tokens x 4 cols
    int cg = tid & 15, tg = tid >> 4;
    int c0 = cg*4, tl0 = tg*4;
    float aq[4][4], av[4][4];
    for (int i=0;i<4;i++) for (int j=0;j<4;j++){ aq[i][j]=0.f; av[i][j]=0.f; }
    for (int f = 0; f < 64; f++) {
        float4 wq4 = *(const float4*)&wqk[f*64 + c0];
        float4 wv4 = *(const float4*)&wv [f*64 + c0];
        float xv[4];
        for (int i=0;i<4;i++) xv[i] = xln[tl0+i][f];
        for (int i=0;i<4;i++) {
            aq[i][0] += xv[i]*wq4.x; aq[i][1] += xv[i]*wq4.y;
            aq[i][2] += xv[i]*wq4.z; aq[i][3] += xv[i]*wq4.w;
            av[i][0] += xv[i]*wv4.x; av[i][1] += xv[i]*wv4.y;
            av[i][2] += xv[i]*wv4.z; av[i][3] += xv[i]*wv4.w;
        }
    }
    int head = c0 >> 4;
    int dh0  = c0 & 15;
    for (int i=0;i<4;i++) {
        int t = t0 + tl0 + i;
        float4 q4; q4.x=aq[i][0]; q4.y=aq[i][1]; q4.z=aq[i][2]; q4.w=aq[i][3];
        float4 v4; v4.x=av[i][0]; v4.y=av[i][1]; v4.z=av[i][2]; v4.w=av[i][3];
        *(float4*)&qk[((size_t)(b*NHEADS+head)*LSEQ + t)*DHD + dh0] = q4;
        *(float4*)&v [((size_t)(b*NHEADS+head)*LSEQ + t)*DHD + dh0] = v4;
        qkt[tl0+i][c0+0] = aq[i][0]; qkt[tl0+i][c0+1] = aq[i][1];
        qkt[tl0+i][c0+2] = aq[i][2]; qkt[tl0+i][c0+3] = aq[i][3];
    }
    __syncthreads();
    // buckets: thread = (token, head)
    int ttk = tid >> 2, hh = tid & 3;
    float qf[16];
    for (int f=0; f<16; f++) qf[f] = qkt[ttk][hh*16+f];
    int tglob = t0 + ttk;
    for (int nh = 0; nh < NHASH; nh++) {
        float rv[10];
        for (int i=0;i<10;i++) {
            float acc = 0.f;
            for (int f=0; f<16; f++) acc += qf[f]*rots[(f*NHASH+nh)*10 + i];
            rv[i] = acc;
        }
        float best = rv[0]; int bi = 0;
        for (int i=1;i<10;i++) if (rv[i] > best) { best = rv[i]; bi = i; }
        for (int i=0;i<10;i++) if (-rv[i] > best) { best = -rv[i]; bi = 10+i; }
        buckets[((size_t)(b*NHEADS+hh)*NHASH + nh)*LSEQ + tglob] = bi;
    }
}

// ---------------- counting sort per (bh, hash): stable, ballot-ranked ----------------
// one wave per (bh,hash) group; grid 256, block 64
__global__ __launch_bounds__(64) void k_sort(
    const int* __restrict__ buckets, int* __restrict__ sorted)
{
    __shared__ int hist[20];
    __shared__ int startl[20];
    int lane = threadIdx.x;
    int gidx = blockIdx.x;
    const int* bk = buckets + (size_t)gidx * LSEQ;
    int* dst = sorted + (size_t)gidx * LSEQ;
    if (lane < 20) hist[lane] = 0;
    __syncthreads();
    int myb[20];
    for (int ch = 0; ch < 20; ch++) {
        myb[ch] = bk[ch*64 + lane];
        atomicAdd(&hist[myb[ch]], 1);
    }
    __syncthreads();
    if (lane == 0) {
        int acc = 0;
        for (int b2 = 0; b2 < 20; b2++) { startl[b2] = acc; acc += hist[b2]; }
    }
    __syncthreads();
    unsigned long long below = (lane == 63) ? 0x7fffffffffffffffull
                                            : ((1ull << lane) - 1ull);
    for (int ch = 0; ch < 20; ch++) {
        int bv = myb[ch];
        unsigned long long mymask = 0, ownmask = 0;
        #pragma unroll
        for (int b2 = 0; b2 < 20; b2++) {
            unsigned long long m2 = __ballot(bv == b2);
            if (b2 == bv)   mymask  = m2;
            if (b2 == lane) ownmask = m2;
        }
        int rank = __popcll(mymask & below);
        int base = startl[bv];
        dst[base + rank] = ch*64 + lane;
        __syncthreads();
        if (lane < 20) startl[lane] += __popcll(ownmask);
        __syncthreads();
    }
}

// ---------------- chunked attention v2: register dots, shuffle softmax ----------------
// one (bh, chunk) per block; grid 5120, block 256
// thread = (2 q-rows {qh, qh+32}) x (16 k-cols kj = 8k+ko)
__global__ __launch_bounds__(256) void k_attn(
    const float* __restrict__ qk, const float* __restrict__ v,
    const int* __restrict__ sorted, float* __restrict__ o_hash, float* __restrict__ slog)
{
    __shared__ float rows[128][20];   // raw qk rows; stride 20: 16B-aligned, conflict-free for kj=8k+ko
    __shared__ float vs[128][20];
    __shared__ float ninv[128];
    __shared__ int   qpos[64];
    __shared__ int   kpos[128];
    int tid = threadIdx.x;
    int bh = blockIdx.x / NCHUNK;
    int c  = blockIdx.x % NCHUNK;
    int h  = c / NBUK, cc = c % NBUK;
    int cp = (c + NCHUNK - 1) % NCHUNK;
    int hp = cp / NBUK, ccp = cp % NBUK;
    if (tid < 64) {
        int p = sorted[((size_t)bh*NHASH + h)*LSEQ + cc*64 + tid];
        qpos[tid] = p; kpos[tid] = p;
    } else if (tid < 128) {
        int j = tid - 64;
        kpos[64+j] = sorted[((size_t)bh*NHASH + hp)*LSEQ + ccp*64 + j];
    }
    __syncthreads();
    if (tid < 128) {
        int pos = kpos[tid];
        const float4* qrow = (const float4*)(qk + ((size_t)bh*LSEQ + pos)*DHD);
        float4 r0 = qrow[0], r1 = qrow[1], r2 = qrow[2], r3 = qrow[3];
        float nsq = r0.x*r0.x + r0.y*r0.y + r0.z*r0.z + r0.w*r0.w
                  + r1.x*r1.x + r1.y*r1.y + r1.z*r1.z + r1.w*r1.w
                  + r2.x*r2.x + r2.y*r2.y + r2.z*r2.z + r2.w*r2.w
                  + r3.x*r3.x + r3.y*r3.y + r3.z*r3.z + r3.w*r3.w;
        *(float4*)&rows[tid][0]  = r0;
        *(float4*)&rows[tid][4]  = r1;
        *(float4*)&rows[tid][8]  = r2;
        *(float4*)&rows[tid][12] = r3;
        ninv[tid] = 1.f / fmaxf(sqrtf(nsq), 1e-12f);
        const float4* vrow = (const float4*)(v + ((size_t)bh*LSEQ + pos)*DHD);
        *(float4*)&vs[tid][0]  = vrow[0];
        *(float4*)&vs[tid][4]  = vrow[1];
        *(float4*)&vs[tid][8]  = vrow[2];
        *(float4*)&vs[tid][12] = vrow[3];
    }
    __syncthreads();

    int qh = tid >> 3;      // 0..31 -> q rows qh, qh+32
    int ko = tid & 7;       // k-col subgroup
    float qa[16], qb[16];
    {
        float4 a0 = *(const float4*)&rows[qh][0],  a1 = *(const float4*)&rows[qh][4];
        float4 a2 = *(const float4*)&rows[qh][8],  a3 = *(const float4*)&rows[qh][12];
        qa[0]=a0.x; qa[1]=a0.y; qa[2]=a0.z; qa[3]=a0.w;
        qa[4]=a1.x; qa[5]=a1.y; qa[6]=a1.z; qa[7]=a1.w;
        qa[8]=a2.x; qa[9]=a2.y; qa[10]=a2.z; qa[11]=a2.w;
        qa[12]=a3.x; qa[13]=a3.y; qa[14]=a3.z; qa[15]=a3.w;
        float4 b0 = *(const float4*)&rows[qh+32][0],  b1 = *(const float4*)&rows[qh+32][4];
        float4 b2 = *(const float4*)&rows[qh+32][8],  b3 = *(const float4*)&rows[qh+32][12];
        qb[0]=b0.x; qb[1]=b0.y; qb[2]=b0.z; qb[3]=b0.w;
        qb[4]=b1.x; qb[5]=b1.y; qb[6]=b1.z; qb[7]=b1.w;
        qb[8]=b2.x; qb[9]=b2.y; qb[10]=b2.z; qb[11]=b2.w;
        qb[12]=b3.x; qb[13]=b3.y; qb[14]=b3.z; qb[15]=b3.w;
    }
    int pa = qpos[qh], pb = qpos[qh+32];

    float da[16], db[16];
    #pragma unroll
    for (int k = 0; k < 16; k++) {
        int kj = k*8 + ko;
        float4 r0 = *(const float4*)&rows[kj][0],  r1 = *(const float4*)&rows[kj][4];
        float4 r2 = *(const float4*)&rows[kj][8],  r3 = *(const float4*)&rows[kj][12];
        float sa_ = qa[0]*r0.x + qa[1]*r0.y + qa[2]*r0.z + qa[3]*r0.w
                  + qa[4]*r1.x + qa[5]*r1.y + qa[6]*r1.z + qa[7]*r1.w
                  + qa[8]*r2.x + qa[9]*r2.y + qa[10]*r2.z + qa[11]*r2.w
                  + qa[12]*r3.x + qa[13]*r3.y + qa[14]*r3.z + qa[15]*r3.w;
        float sb_ = qb[0]*r0.x + qb[1]*r0.y + qb[2]*r0.z + qb[3]*r0.w
                  + qb[4]*r1.x + qb[5]*r1.y + qb[6]*r1.z + qb[7]*r1.w
                  + qb[8]*r2.x + qb[9]*r2.y + qb[10]*r2.z + qb[11]*r2.w
                  + qb[12]*r3.x + qb[13]*r3.y + qb[14]*r3.z + qb[15]*r3.w;
        float sc = ninv[kj]*0.25f;
        int kp = kpos[kj];
        da[k] = (kp == pa) ? -5e4f : sa_*sc;
        db[k] = (kp == pb) ? -5e4f : sb_*sc;
    }
    // softmax over 128 = 16 local x 8 lanes
    float ma = -3.4e38f, mb = -3.4e38f;
    #pragma unroll
    for (int k = 0; k < 16; k++) { ma = fmaxf(ma, da[k]); mb = fmaxf(mb, db[k]); }
    ma = fmaxf(ma, __shfl_xor(ma, 1)); ma = fmaxf(ma, __shfl_xor(ma, 2)); ma = fmaxf(ma, __shfl_xor(ma, 4));
    mb = fmaxf(mb, __shfl_xor(mb, 1)); mb = fmaxf(mb, __shfl_xor(mb, 2)); mb = fmaxf(mb, __shfl_xor(mb, 4));
    float sa = 0.f, sb = 0.f;
    #pragma unroll
    for (int k = 0; k < 16; k++) {
        da[k] = __expf(da[k] - ma); sa += da[k];
        db[k] = __expf(db[k] - mb); sb += db[k];
    }
    sa += __shfl_xor(sa, 1); sa += __shfl_xor(sa, 2); sa += __shfl_xor(sa, 4);
    sb += __shfl_xor(sb, 1); sb += __shfl_xor(sb, 2); sb += __shfl_xor(sb, 4);
    float ia = 1.f/sa, ib = 1.f/sb;
    float lsa = ma + __logf(sa), lsb = mb + __logf(sb);

    // PV partials
    float4 oa0={0,0,0,0}, oa1={0,0,0,0}, oa2={0,0,0,0}, oa3={0,0,0,0};
    float4 ob0={0,0,0,0}, ob1={0,0,0,0}, ob2={0,0,0,0}, ob3={0,0,0,0};
    #pragma unroll
    for (int k = 0; k < 16; k++) {
        int kj = k*8 + ko;
        float4 v0 = *(const float4*)&vs[kj][0],  v1 = *(const float4*)&vs[kj][4];
        float4 v2 = *(const float4*)&vs[kj][8],  v3 = *(const float4*)&vs[kj][12];
        float p = da[k], q = db[k];
        oa0.x += p*v0.x; oa0.y += p*v0.y; oa0.z += p*v0.z; oa0.w += p*v0.w;
        oa1.x += p*v1.x; oa1.y += p*v1.y; oa1.z += p*v1.z; oa1.w += p*v1.w;
        oa2.x += p*v2.x; oa2.y += p*v2.y; oa2.z += p*v2.z; oa2.w += p*v2.w;
        oa3.x += p*v3.x; oa3.y += p*v3.y; oa3.z += p*v3.z; oa3.w += p*v3.w;
        ob0.x += q*v0.x; ob0.y += q*v0.y; ob0.z += q*v0.z; ob0.w += q*v0.w;
        ob1.x += q*v1.x; ob1.y += q*v1.y; ob1.z += q*v1.z; ob1.w += q*v1.w;
        ob2.x += q*v2.x; ob2.y += q*v2.y; ob2.z += q*v2.z; ob2.w += q*v2.w;
        ob3.x += q*v3.x; ob3.y += q*v3.y; ob3.z += q*v3.z; ob3.w += q*v3.w;
    }
    // reduce across the 8 ko lanes
    #define RED8(x) { x += __shfl_xor(x, 1); x += __shfl_xor(x, 2); x += __shfl_xor(x, 4); }
    RED8(oa0.x) RED8(oa0.y) RED8(oa0.z) RED8(oa0.w)
    RED8(oa1.x) RED8(oa1.y) RED8(oa1.z) RED8(oa1.w)
    RED8(oa2.x) RED8(oa2.y) RED8(oa2.z) RED8(oa2.w)
    RED8(oa3.x) RED8(oa3.y) RED8(oa3.z) RED8(oa3.w)
    RED8(ob0.x) RED8(ob0.y) RED8(ob0.z) RED8(ob0.w)
    RED8(ob1.x) RED8(ob1.y) RED8(ob1.z) RED8(ob1.w)
    RED8(ob2.x) RED8(ob2.y) RED8(ob2.z) RED8(ob2.w)
    RED8(ob3.x) RED8(ob3.y) RED8(ob3.z) RED8(ob3.w)
    #undef RED8
    if (ko == 0) {
        size_t basea = (((size_t)bh*NHASH + h)*LSEQ + pa)*DHD;
        float4 w0; w0.x=oa0.x*ia; w0.y=oa0.y*ia; w0.z=oa0.z*ia; w0.w=oa0.w*ia;
        float4 w1; w1.x=oa1.x*ia; w1.y=oa1.y*ia; w1.z=oa1.z*ia; w1.w=oa1.w*ia;
        float4 w2; w2.x=oa2.x*ia; w2.y=oa2.y*ia; w2.z=oa2.z*ia; w2.w=oa2.w*ia;
        float4 w3; w3.x=oa3.x*ia; w3.y=oa3.y*ia; w3.z=oa3.z*ia; w3.w=oa3.w*ia;
        *(float4*)&o_hash[basea+0] = w0; *(float4*)&o_hash[basea+4] = w1;
        *(float4*)&o_hash[basea+8] = w2; *(float4*)&o_hash[basea+12] = w3;
        slog[((size_t)bh*NHASH + h)*LSEQ + pa] = lsa;
        size_t baseb = (((size_t)bh*NHASH + h)*LSEQ + pb)*DHD;
        float4 u0; u0.x=ob0.x*ib; u0.y=ob0.y*ib; u0.z=ob0.z*ib; u0.w=ob0.w*ib;
        float4 u1; u1.x=ob1.x*ib; u1.y=ob1.y*ib; u1.z=ob1.z*ib; u1.w=ob1.w*ib;
        float4 u2; u2.x=ob2.x*ib; u2.y=ob2.y*ib; u2.z=ob2.z*ib; u2.w=ob2.w*ib;
        float4 u3; u3.x=ob3.x*ib; u3.y=ob3.y*ib; u3.z=ob3.z*ib; u3.w=ob3.w*ib;
        *(float4*)&o_hash[baseb+0] = u0; *(float4*)&o_hash[baseb+4] = u1;
        *(float4*)&o_hash[baseb+8] = u2; *(float4*)&o_hash[baseb+12] = u3;
        slog[((size_t)bh*NHASH + h)*LSEQ + pb] = lsb;
    }
}

// ---------------- hash-round combine + output proj + residual into x1 ----------------
// block = 64 tokens of one batch; grid 320
__global__ __launch_bounds__(256) void k_combine(
    const float* __restrict__ o_hash, const float* __restrict__ slog,
    const float* __restrict__ wo_w, const float* __restrict__ wo_b, float* __restrict__ x1)
{
    __shared__ float att[64][65];
    int tid = threadIdx.x;
    int b  = blockIdx.x / 20;
    int t0 = (blockIdx.x % 20) * 64;
    int ttk = tid >> 2, head = tid & 3;
    int t = t0 + ttk;
    int bh = b*NHEADS + head;
    float sl[4];
    for (int nh=0;nh<4;nh++) sl[nh] = slog[((size_t)bh*NHASH + nh)*LSEQ + t];
    float mx = fmaxf(fmaxf(sl[0],sl[1]), fmaxf(sl[2],sl[3]));
    float wsum = 0.f; float wv[4];
    for (int nh=0;nh<4;nh++){ wv[nh] = __expf(sl[nh]-mx); wsum += wv[nh]; }
    float invs = 1.f/wsum;
    float a[16];
    for (int d=0;d<16;d++) a[d]=0.f;
    for (int nh=0;nh<4;nh++){
        const float4* orow = (const float4*)(o_hash + (((size_t)bh*NHASH + nh)*LSEQ + t)*DHD);
        float wn = wv[nh]*invs;
        float4 A=orow[0], B=orow[1], C=orow[2], Dq=orow[3];
        a[0]+=wn*A.x;  a[1]+=wn*A.y;  a[2]+=wn*A.z;  a[3]+=wn*A.w;
        a[4]+=wn*B.x;  a[5]+=wn*B.y;  a[6]+=wn*B.z;  a[7]+=wn*B.w;
        a[8]+=wn*C.x;  a[9]+=wn*C.y;  a[10]+=wn*C.z; a[11]+=wn*C.w;
        a[12]+=wn*Dq.x;a[13]+=wn*Dq.y;a[14]+=wn*Dq.z;a[15]+=wn*Dq.w;
    }
    for (int d=0;d<16;d++) att[ttk][head*16+d] = a[d];
    __syncthreads();
    int cg = tid & 15, tg = tid >> 4;
    int c0 = cg*4, tl0 = tg*4;
    float acc[4][4];
    for (int i=0;i<4;i++) for (int j=0;j<4;j++) acc[i][j]=0.f;
    for (int f=0; f<64; f++){
        float4 w4 = *(const float4*)&wo_w[f*64 + c0];
        float xv[4];
        for (int i=0;i<4;i++) xv[i] = att[tl0+i][f];
        for (int i=0;i<4;i++){
            acc[i][0]+=xv[i]*w4.x; acc[i][1]+=xv[i]*w4.y;
            acc[i][2]+=xv[i]*w4.z; acc[i][3]+=xv[i]*w4.w;
        }
    }
    float4 bb = *(const float4*)&wo_b[c0];
    for (int i=0;i<4;i++){
        size_t idx = ((size_t)b*LSEQ + (t0 + tl0 + i))*DM + c0;
        float4 cur = *(float4*)&x1[idx];
        cur.x += acc[i][0]+bb.x; cur.y += acc[i][1]+bb.y;
        cur.z += acc[i][2]+bb.z; cur.w += acc[i][3]+bb.w;
        *(float4*)&x1[idx] = cur;
    }
}

// ---------------- LN2 + W1 + gelu -> mid ----------------
// block = 32 tokens; grid 640
__global__ __launch_bounds__(256) void k_ff1(
    const float* __restrict__ x1, const float* __restrict__ g, const float* __restrict__ bta,
    const float* __restrict__ w1, const float* __restrict__ b1, float* __restrict__ mid)
{
    __shared__ float w1s[16*256];
    __shared__ float xln[32][65];
    __shared__ float ps[32][8], pq[32][8];
    int tid = threadIdx.x;
    int tbase = blockIdx.x * 32;
    int r = tid >> 3, qq = tid & 7;
    const float* xr = x1 + (size_t)(tbase + r)*DM;
    float vals[8]; float s = 0.f, ss = 0.f;
    for (int i=0;i<8;i++){ float vv = xr[qq*8+i]; vals[i]=vv; s+=vv; ss+=vv*vv; }
    ps[r][qq]=s; pq[r][qq]=ss;
    __syncthreads();
    float m=0.f, vr=0.f;
    for (int k2=0;k2<8;k2++){ m+=ps[r][k2]; vr+=pq[r][k2]; }
    m *= (1.f/64.f); vr = vr*(1.f/64.f) - m*m;
    float rstd = 1.f/sqrtf(vr+1e-5f);
    for (int i=0;i<8;i++){ int cidx=qq*8+i; xln[r][cidx] = (vals[i]-m)*rstd*g[cidx]+bta[cidx]; }
    float acc[4][8];
    for (int i=0;i<4;i++) for (int k2=0;k2<8;k2++) acc[i][k2]=0.f;
    int tg = tid >> 5;      // 8 groups of 4 tokens
    int cg = tid & 31;      // out col = cg + 32*k2
    int tl0 = tg*4;
    for (int fc = 0; fc < 4; fc++) {
        __syncthreads();
        for (int j = tid; j < 1024; j += 256)
            *(float4*)&w1s[j*4] = *(const float4*)&w1[fc*4096 + j*4];
        __syncthreads();
        for (int fl = 0; fl < 16; fl++) {
            int f = fc*16 + fl;
            float xv[4];
            for (int i=0;i<4;i++) xv[i] = xln[tl0+i][f];
            for (int k2=0;k2<8;k2++) {
                float wvv = w1s[fl*256 + cg + 32*k2];
                for (int i=0;i<4;i++) acc[i][k2] += xv[i]*wvv;
            }
        }
    }
    for (int k2=0;k2<8;k2++){
        int cidx = cg + 32*k2;
        float bb = b1[cidx];
        for (int i=0;i<4;i++){
            float xx = acc[i][k2] + bb;
            float ge = 0.5f*xx*(1.f + erff(xx*0.70710678118654752f));
            mid[(size_t)(tbase + tl0 + i)*FFD + cidx] = ge;
        }
    }
}

// ---------------- mid @ W2 + b2 -> residual into x2 ----------------
// block = 64 tokens; grid 320
__global__ __launch_bounds__(256) void k_ff2(
    const float* __restrict__ mid, const float* __restrict__ w2, const float* __restrict__ b2,
    float* __restrict__ x2)
{
    __shared__ float mids[64][65];
    int tid = threadIdx.x;
    int tbase = blockIdx.x * 64;
    int tg = tid >> 4, cg = tid & 15;
    int tl0 = tg*4, c0 = cg*4;
    float acc[4][4];
    for (int i=0;i<4;i++) for (int j=0;j<4;j++) acc[i][j]=0.f;
    for (int fc = 0; fc < 4; fc++) {
        __syncthreads();
        for (int j = tid; j < 1024; j += 256) {
            int row = j >> 4; int col4 = (j & 15) * 4;
            float4 vv = *(const float4*)&mid[(size_t)(tbase+row)*FFD + fc*64 + col4];
            mids[row][col4+0]=vv.x; mids[row][col4+1]=vv.y;
            mids[row][col4+2]=vv.z; mids[row][col4+3]=vv.w;
        }
        __syncthreads();
        for (int fl = 0; fl < 64; fl++) {
            float4 wv4 = *(const float4*)&w2[(fc*64+fl)*64 + c0];
            float mv[4];
            for (int i=0;i<4;i++) mv[i] = mids[tl0+i][fl];
            for (int i=0;i<4;i++){
                acc[i][0]+=mv[i]*wv4.x; acc[i][1]+=mv[i]*wv4.y;
                acc[i][2]+=mv[i]*wv4.z; acc[i][3]+=mv[i]*wv4.w;
            }
        }
    }
    float4 bb = *(const float4*)&b2[c0];
    for (int i=0;i<4;i++){
        size_t idx = ((size_t)(tbase + tl0 + i))*DM + c0;
        float4 cur = *(float4*)&x2[idx];
        cur.x += acc[i][0]+bb.x; cur.y += acc[i][1]+bb.y;
        cur.z += acc[i][2]+bb.z; cur.w += acc[i][3]+bb.w;
        *(float4*)&x2[idx] = cur;
    }
}

// ---------------- output proj: y = 0.5*(x1+x2) @ out_w + out_b, crop to 1250 ----------------
__global__ __launch_bounds__(256) void k_out(
    const float* __restrict__ x1, const float* __restrict__ x2,
    const float* __restrict__ out_w, const float* __restrict__ out_b, float* __restrict__ y)
{
    int idx = blockIdx.x * 256 + threadIdx.x;
    if (idx >= NBATCH * L0SEQ) return;
    int b = idx / L0SEQ, t = idx % L0SEQ;
    const float* r1 = x1 + ((size_t)b*LSEQ + t)*DM;
    const float* r2 = x2 + ((size_t)b*LSEQ + t)*DM;
    float s = 0.f;
    for (int d = 0; d < DM; d++) s += (r1[d]+r2[d])*0.5f*out_w[d];
    y[idx] = s + out_b[0];
}

extern "C" void kernel_launch(void* const* d_in, const int* in_sizes, int n_in,
                              void* d_out, int out_size, void* d_ws, size_t ws_size,
                              hipStream_t stream)
{
    const float* wave  = (const float*)d_in[0];
    const float* in_w  = (const float*)d_in[1];
    const float* in_b  = (const float*)d_in[2];
    const float* ln1_g = (const float*)d_in[3];
    const float* ln1_b = (const float*)d_in[4];
    const float* wqk   = (const float*)d_in[5];
    const float* wv    = (const float*)d_in[6];
    const float* wo_w  = (const float*)d_in[7];
    const float* wo_b  = (const float*)d_in[8];
    const float* rot   = (const float*)d_in[9];
    const float* ln2_g = (const float*)d_in[10];
    const float* ln2_b = (const float*)d_in[11];
    const float* w1    = (const float*)d_in[12];
    const float* b1    = (const float*)d_in[13];
    const float* w2    = (const float*)d_in[14];
    const float* b2    = (const float*)d_in[15];
    const float* out_w = (const float*)d_in[16];
    const float* out_b = (const float*)d_in[17];
    float* y = (float*)d_out;

    float* ws = (float*)d_ws;
    float* x1     = ws;                  // XSZ
    float* x2     = x1 + XSZ;            // XSZ
    float* qkb    = x2 + XSZ;            // QKSZ
    float* vb     = qkb + QKSZ;          // QKSZ
    float* o_hash = vb + QKSZ;           // OHSZ
    float* slogb  = o_hash + OHSZ;       // SLSZ
    int* buckets  = (int*)(slogb + SLSZ); // SLSZ ints
    int* sorted   = buckets + SLSZ;      // SLSZ ints
    float* mid    = o_hash;              // reuse (disjoint lifetime within a layer)

    k_embed<<<XSZ/256, 256, 0, stream>>>(wave, in_w, in_b, x1, x2);
    for (int layer = 0; layer < 4; layer++) {
        k_qkv<<<320, 256, 0, stream>>>(x2, ln1_g + layer*64, ln1_b + layer*64,
                                       wqk + layer*4096, wv + layer*4096, rot + layer*640,
                                       qkb, vb, buckets);
        k_sort<<<256, 64, 0, stream>>>(buckets, sorted);
        k_attn<<<NBH*NCHUNK, 256, 0, stream>>>(qkb, vb, sorted, o_hash, slogb);
        k_combine<<<320, 256, 0, stream>>>(o_hash, slogb, wo_w + layer*4096, wo_b + layer*64, x1);
        k_ff1<<<640, 256, 0, stream>>>(x1, ln2_g + layer*64, ln2_b + layer*64,
                                       w1 + layer*16384, b1 + layer*256, mid);
        k_ff2<<<320, 256, 0, stream>>>(mid, w2 + layer*16384, b2 + layer*64, x2);
    }
    k_out<<<(NBATCH*L0SEQ + 255)/256, 256, 0, stream>>>(x1, x2, out_w, out_b, y);
}